// Round 3
// baseline (194.149 us; speedup 1.0000x reference)
//
#include <hip/hip_runtime.h>
#include <hip/hip_bf16.h>

// GAT layer, B=8 N=1024 IN=128 H=4 D=32. Inputs f32, OUTPUT f32 (reference
// returns f32; the harness compares against a bf16-rounded ref with 2% thr).
// fp32 internal, W staged as bf16 in LDS (error ~2e-3 << 1.48e-2 threshold).
//
// Math: h = x @ W^T  [B,N,H,D];  s=h.a_src, t=h.a_dst per (b,n,h)
//   w_qk = exp(LeakyReLU_{0.2}(s_q + t_k)) * alive_k
//        = exp(s_q)*e1_k        if s_q+t_k >= 0
//          exp(.2 s_q)*e2_k     else
//   with e1_k = alive_k*exp(t_k), e2_k = alive_k*exp(.2 t_k)  (precomputed)
//   out_q = (A*sum_cond e1_k h_k + Bv*sum_!cond e2_k h_k) / (A*den1 + Bv*den2)
//   (exp(s_q) factors cancel in the ratio only partially -- kept explicitly)

#define B_   8
#define N_   1024
#define IND  128
#define H_   4
#define D_   32
#define NEG  0.2f
#define QT   32
#define KT   256

typedef float  float4_ __attribute__((ext_vector_type(4)));

__device__ __forceinline__ float bf2f(ushort u) {
    union { unsigned int i; float f; } v; v.i = ((unsigned int)u) << 16; return v.f;
}
__device__ __forceinline__ ushort f2bf(float f) {
    // round-to-nearest-even bf16
    union { float f; unsigned int i; } v; v.f = f;
    unsigned int lsb = (v.i >> 16) & 1u;
    v.i += 0x7fffu + lsb;
    return (ushort)(v.i >> 16);
}

// ---------------- Kernel 1: h = x@W^T, alphas, exp factors ----------------
// grid = B*N blocks, 128 threads. Thread t owns output column t (= hd*32+d).
__global__ __launch_bounds__(128) void k_h_alpha(
    const float* __restrict__ x,      // [B*N,128] f32
    const float* __restrict__ alive,  // [B*N] f32
    const float* __restrict__ W,      // [128,128] f32
    const float* __restrict__ a_src,  // [128] f32 (flattened [4,32])
    const float* __restrict__ a_dst,  // [128]
    float* __restrict__ h_ws,          // [B*N*128]
    float* __restrict__ s_ws,          // [B*N*4]
    float* __restrict__ t_ws,          // [B*N*4]
    float* __restrict__ e1_ws,         // [B*N*4]
    float* __restrict__ e2_ws)         // [B*N*4]
{
    __shared__ float  xs[IND];
    __shared__ ushort Wl[IND][134];    // bf16 W; 134 ushorts = 67 words (odd) -> 2-way max
    __shared__ float  asrc[IND], adst[IND];

    const int r = blockIdx.x;          // b*N+n
    const int t = threadIdx.x;         // 0..127

    xs[t]   = x[r * IND + t];
    asrc[t] = a_src[t];
    adst[t] = a_dst[t];

    // stage W: read f32 pairs coalesced, convert+pack to bf16 pairs in LDS
    const float2* Wf2 = reinterpret_cast<const float2*>(W);
    #pragma unroll
    for (int i = t; i < 8192; i += 128) {
        float2 w2 = Wf2[i];
        unsigned int u = ((unsigned int)f2bf(w2.y) << 16) | (unsigned int)f2bf(w2.x);
        int row = i >> 6;          // 64 uint-slots per row
        int c2  = i & 63;
        reinterpret_cast<unsigned int*>(Wl[row])[c2] = u;
    }
    __syncthreads();

    const unsigned int* wrow = reinterpret_cast<const unsigned int*>(Wl[t]);
    float acc = 0.f;
    #pragma unroll
    for (int j = 0; j < 64; ++j) {
        unsigned int u = wrow[j];
        acc = fmaf(xs[2 * j],     bf2f((ushort)(u & 0xffffu)), acc);
        acc = fmaf(xs[2 * j + 1], bf2f((ushort)(u >> 16)),     acc);
    }
    h_ws[(size_t)r * IND + t] = acc;

    // per-head (32-lane) reductions for s = h.a_src, t = h.a_dst
    float ps = acc * asrc[t];
    float pt = acc * adst[t];
    #pragma unroll
    for (int m = 16; m >= 1; m >>= 1) {
        ps += __shfl_xor(ps, m);
        pt += __shfl_xor(pt, m);
    }
    if ((t & 31) == 0) {
        int hd  = t >> 5;
        int idx = r * H_ + hd;
        s_ws[idx] = ps;
        t_ws[idx] = pt;
        float am = (alive[r] >= 0.5f) ? 1.f : 0.f;
        e1_ws[idx] = am * expf(pt);
        e2_ws[idx] = am * expf(NEG * pt);
    }
}

// ---------------- Kernel 2: attention (brute force, factored exp) ----------
// grid = (N/QT, H, B), 256 threads. 8 threads per query, 4 dims each.
__global__ __launch_bounds__(256) void k_attn(
    const float* __restrict__ h_ws,
    const float* __restrict__ s_ws,
    const float* __restrict__ t_ws,
    const float* __restrict__ e1_ws,
    const float* __restrict__ e2_ws,
    float* __restrict__ out)
{
    __shared__ float hl[KT][D_];                 // 32 KB
    __shared__ float tl[KT], e1l[KT], e2l[KT];   // 3 KB

    const int tid = threadIdx.x;
    const int ql  = tid >> 3;       // 0..31
    const int sub = tid & 7;        // 0..7 -> dims sub*4..sub*4+3
    const int hd  = blockIdx.y;
    const int b   = blockIdx.z;
    const int q   = blockIdx.x * QT + ql;

    const float sq = s_ws[((size_t)(b * N_ + q)) * H_ + hd];

    float4_ acc1 = {0.f, 0.f, 0.f, 0.f};
    float4_ acc2 = {0.f, 0.f, 0.f, 0.f};
    float den1 = 0.f, den2 = 0.f;

    for (int k0 = 0; k0 < N_; k0 += KT) {
        __syncthreads();
        // stage KT key rows: thread i loads row i (32 floats = 8x float4)
        {
            const size_t krow = (size_t)(b * N_ + k0 + tid);
            const float4_* src = reinterpret_cast<const float4_*>(&h_ws[krow * IND + hd * D_]);
            float4_* dst = reinterpret_cast<float4_*>(hl[tid]);
            #pragma unroll
            for (int j = 0; j < 8; ++j) dst[j] = src[j];
            const size_t gi = krow * H_ + hd;
            tl[tid]  = t_ws[gi];
            e1l[tid] = e1_ws[gi];
            e2l[tid] = e2_ws[gi];
        }
        __syncthreads();

        #pragma unroll 4
        for (int k = 0; k < KT; ++k) {
            float tk = tl[k];
            bool  c  = (sq + tk) >= 0.f;
            float c1 = c ? e1l[k] : 0.f;
            float c2 = c ? 0.f : e2l[k];
            den1 += c1;
            den2 += c2;
            const float4_ h4 = *reinterpret_cast<const float4_*>(&hl[k][sub * 4]);
            acc1 += c1 * h4;
            acc2 += c2 * h4;
        }
    }

    const float A  = expf(sq);
    const float Bv = expf(NEG * sq);
    const float den = A * den1 + Bv * den2;
    const float inv = (den != 0.f) ? 1.f / den : 0.f;   // all-keys-dead -> 0 (nan_to_num)

    float4_ r;
    #pragma unroll
    for (int j = 0; j < 4; ++j)
        r[j] = (A * acc1[j] + Bv * acc2[j]) * inv;
    *reinterpret_cast<float4_*>(&out[((size_t)(b * N_ + q)) * IND + hd * D_ + sub * 4]) = r;
}

extern "C" void kernel_launch(void* const* d_in, const int* in_sizes, int n_in,
                              void* d_out, int out_size, void* d_ws, size_t ws_size,
                              hipStream_t stream) {
    const float* x     = (const float*)d_in[0];
    const float* alive = (const float*)d_in[1];
    const float* W     = (const float*)d_in[2];
    const float* a_src = (const float*)d_in[3];
    const float* a_dst = (const float*)d_in[4];
    float* out = (float*)d_out;   // reference output dtype is float32

    float* h_ws  = (float*)d_ws;                 // 1,048,576 f32 (4 MiB)
    float* s_ws  = h_ws  + (size_t)B_ * N_ * IND;
    float* t_ws  = s_ws  + (size_t)B_ * N_ * H_;
    float* e1_ws = t_ws  + (size_t)B_ * N_ * H_;
    float* e2_ws = e1_ws + (size_t)B_ * N_ * H_; // total ~4.5 MiB scratch

    k_h_alpha<<<B_ * N_, 128, 0, stream>>>(x, alive, W, a_src, a_dst,
                                           h_ws, s_ws, t_ws, e1_ws, e2_ws);

    dim3 g2(N_ / QT, H_, B_);
    k_attn<<<g2, 256, 0, stream>>>(h_ws, s_ws, t_ws, e1_ws, e2_ws, out);
}

// Round 4
// 113.381 us; speedup vs baseline: 1.7124x; 1.7124x over previous
//
#include <hip/hip_runtime.h>
#include <hip/hip_bf16.h>

// GAT layer, B=8 N=1024 IN=128 H=4 D=32. Inputs f32, OUTPUT f32.
//
// k1: h = x@W^T (W bf16 in LDS), s/t/e1/e2 per (row,head). 4 rows/block.
// k2: O(N*D) attention via rank-1-logit factorization:
//   w_qk = exp(LR(s_q+t_k))*alive_k = A_q*e1_k if t_k >= -s_q else B_q*e2_k
//   sort keys by t per (b,h); each query's cond-set is a suffix at
//   p_q = lowerbound(t_sorted, -s_q). Chunked prefix(e2*h)/suffix(e1*h)
//   scans + <=16-key partials give out_q = (A*S1+B*P2)/(A*d1+B*d2).

#define B_   8
#define N_   1024
#define IND  128
#define H_   4
#define D_   32
#define NEG  0.2f
#define CH   16          // chunk size for scans
#define NCH  (N_ / CH)   // 64 chunks
#define DH   8           // dims per pass (f32 in LDS)
#define NPASS (D_ / DH)  // 4 passes

typedef float float4_ __attribute__((ext_vector_type(4)));

__device__ __forceinline__ float bf2f(ushort u) {
    union { unsigned int i; float f; } v; v.i = ((unsigned int)u) << 16; return v.f;
}
__device__ __forceinline__ ushort f2bf(float f) {
    union { float f; unsigned int i; } v; v.f = f;
    unsigned int lsb = (v.i >> 16) & 1u;
    v.i += 0x7fffu + lsb;
    return (ushort)(v.i >> 16);
}

// ---------------- Kernel 1: h = x@W^T, alphas, exp factors ----------------
// grid = B*N/4 blocks, 512 threads. Thread t: col c=t&127, row r=t>>7 (of 4).
__global__ __launch_bounds__(512) void k_h_alpha(
    const float* __restrict__ x,      // [B*N,128]
    const float* __restrict__ alive,  // [B*N]
    const float* __restrict__ W,      // [128,128]
    const float* __restrict__ a_src,  // [128]
    const float* __restrict__ a_dst,  // [128]
    float* __restrict__ h_ws,         // [B*N*128]
    float* __restrict__ s_ws,         // [B*N*4]
    float* __restrict__ t_ws,         // [B*N*4]
    float* __restrict__ e1_ws,        // [B*N*4]
    float* __restrict__ e2_ws)        // [B*N*4]
{
    __shared__ float  xs[4][IND];
    __shared__ ushort Wl[IND][134];   // bf16 W; 134 ushorts = 67 words (odd)
    __shared__ float  asrc[IND], adst[IND];

    const int t     = threadIdx.x;
    const int rbase = blockIdx.x * 4;
    const int c     = t & 127;
    const int r     = t >> 7;

    xs[r][c] = x[(size_t)(rbase + r) * IND + c];
    if (t < IND) { asrc[t] = a_src[t]; adst[t] = a_dst[t]; }

    const float2* Wf2 = reinterpret_cast<const float2*>(W);
    #pragma unroll
    for (int i = t; i < 8192; i += 512) {
        float2 w2 = Wf2[i];
        unsigned int u = ((unsigned int)f2bf(w2.y) << 16) | (unsigned int)f2bf(w2.x);
        reinterpret_cast<unsigned int*>(Wl[i >> 6])[i & 63] = u;
    }
    __syncthreads();

    const unsigned int* wrow = reinterpret_cast<const unsigned int*>(Wl[c]);
    float acc = 0.f;
    #pragma unroll
    for (int j = 0; j < 64; ++j) {
        unsigned int u = wrow[j];
        acc = fmaf(xs[r][2 * j],     bf2f((ushort)(u & 0xffffu)), acc);
        acc = fmaf(xs[r][2 * j + 1], bf2f((ushort)(u >> 16)),     acc);
    }
    const int row = rbase + r;
    h_ws[(size_t)row * IND + c] = acc;

    float ps = acc * asrc[c];
    float pt = acc * adst[c];
    #pragma unroll
    for (int m = 16; m >= 1; m >>= 1) {
        ps += __shfl_xor(ps, m);
        pt += __shfl_xor(pt, m);
    }
    if ((t & 31) == 0) {
        int idx = row * H_ + (c >> 5);
        s_ws[idx] = ps;
        t_ws[idx] = pt;
        float am = (alive[row] >= 0.5f) ? 1.f : 0.f;
        e1_ws[idx] = am * __expf(pt);
        e2_ws[idx] = am * __expf(NEG * pt);
    }
}

// ---------------- Kernel 2: sorted prefix/suffix-scan attention -----------
// grid = (H, B, 4 query-quarters), 256 threads.
__global__ __launch_bounds__(256) void k_attn2(
    const float* __restrict__ h_ws,
    const float* __restrict__ s_ws,
    const float* __restrict__ t_ws,
    const float* __restrict__ e1_ws,
    const float* __restrict__ e2_ws,
    float* __restrict__ out)
{
    __shared__ float  tS[N_];            // 4KB  sort key (t), sorted asc
    __shared__ ushort kI[N_];            // 2KB  original key index
    __shared__ float  e1S[N_], e2S[N_];  // 8KB  e factors in sorted order
    __shared__ float  hS[N_][DH];        // 32KB h (f32), sorted order, DH dims
    __shared__ ushort pS[256];           // split point per query (0..1024)
    __shared__ float  AS[256], BS[256];  // 2KB  exp(s), exp(.2 s)
    __shared__ float  pre2[NCH + 1][DH]; // prefix sums of e2*h  (2.1KB)
    __shared__ float  suf1[NCH + 2][DH]; // suffix sums of e1*h  (2.2KB)
    __shared__ float  dpre2[NCH + 1];    // prefix of e2
    __shared__ float  dsuf1[NCH + 2];    // suffix of e1

    const int tid  = threadIdx.x;
    const int h    = blockIdx.x;
    const int b    = blockIdx.y;
    const int qz   = blockIdx.z;
    const int base = b * N_;

    // P0: load t, init indices
    #pragma unroll
    for (int i = tid; i < N_; i += 256) {
        tS[i] = t_ws[(size_t)(base + i) * H_ + h];
        kI[i] = (ushort)i;
    }

    // P1: bitonic sort (tS, kI) ascending
    for (int kk = 2; kk <= N_; kk <<= 1) {
        for (int jj = kk >> 1; jj > 0; jj >>= 1) {
            __syncthreads();
            #pragma unroll
            for (int i = tid; i < N_; i += 256) {
                int l = i ^ jj;
                if (l > i) {
                    float a = tS[i], cv = tS[l];
                    bool asc = ((i & kk) == 0);
                    if ((a > cv) == asc) {
                        tS[i] = cv; tS[l] = a;
                        ushort ki = kI[i]; kI[i] = kI[l]; kI[l] = ki;
                    }
                }
            }
        }
    }
    __syncthreads();

    // P2: gather e factors in sorted order; per-query binary search
    #pragma unroll
    for (int i = tid; i < N_; i += 256) {
        int gi = (base + (int)kI[i]) * H_ + h;
        e1S[i] = e1_ws[gi];
        e2S[i] = e2_ws[gi];
    }
    {
        int q = qz * 256 + tid;
        float s = s_ws[(size_t)(base + q) * H_ + h];
        AS[tid] = __expf(s);
        BS[tid] = __expf(NEG * s);
        float tau = -s;
        int lo = 0, hi = N_;
        #pragma unroll
        for (int it = 0; it < 10; ++it) {
            int mid = (lo + hi) >> 1;
            if (tS[mid] >= tau) hi = mid; else lo = mid + 1;
        }
        pS[tid] = (ushort)lo;
    }
    __syncthreads();

    for (int ps_ = 0; ps_ < NPASS; ++ps_) {
        // P3: gather DH dims of h (f32) in sorted order
        {
            const int lane2 = tid & 1;          // 2 lanes x float4 = 8 dims
            const int rs    = tid >> 1;         // 128 rows per iter
            #pragma unroll
            for (int it = 0; it < 8; ++it) {
                int i = rs + it * 128;
                const float4_ v = *reinterpret_cast<const float4_*>(
                    &h_ws[(size_t)(base + (int)kI[i]) * IND + h * D_ + ps_ * DH + lane2 * 4]);
                *reinterpret_cast<float4_*>(&hS[i][lane2 * 4]) = v;
            }
        }
        __syncthreads();

        // P4: chunk sums (both e2-weighted prefix cells and e1-weighted suffix cells)
        #pragma unroll
        for (int cell = tid; cell < NCH * DH; cell += 256) {
            int cc = cell >> 3, d = cell & 7;
            float a2 = 0.f, a1 = 0.f;
            #pragma unroll
            for (int jj = 0; jj < CH; ++jj) {
                int j = cc * CH + jj;
                float hv = hS[j][d];
                a2 = fmaf(e2S[j], hv, a2);
                a1 = fmaf(e1S[j], hv, a1);
            }
            pre2[cc + 1][d] = a2;
            suf1[cc][d]     = a1;
        }
        if (ps_ == 0) {
            if (tid < NCH) {
                float s2 = 0.f;
                #pragma unroll
                for (int jj = 0; jj < CH; ++jj) s2 += e2S[tid * CH + jj];
                dpre2[tid + 1] = s2;
            } else if (tid < 2 * NCH) {
                int cc = tid - NCH;
                float s1 = 0.f;
                #pragma unroll
                for (int jj = 0; jj < CH; ++jj) s1 += e1S[cc * CH + jj];
                dsuf1[cc] = s1;
            }
        }
        __syncthreads();

        // P5: serial scans (register-carried, loads pipeline)
        if (tid < DH) {
            int d = tid; float run = 0.f;
            pre2[0][d] = 0.f;
            for (int cc = 1; cc <= NCH; ++cc) { run += pre2[cc][d]; pre2[cc][d] = run; }
        } else if (tid < 2 * DH) {
            int d = tid - DH; float run = 0.f;
            suf1[NCH][d] = 0.f; suf1[NCH + 1][d] = 0.f;
            for (int cc = NCH - 1; cc >= 0; --cc) { run += suf1[cc][d]; suf1[cc][d] = run; }
        } else if (tid == 2 * DH && ps_ == 0) {
            float run = 0.f; dpre2[0] = 0.f;
            for (int cc = 1; cc <= NCH; ++cc) { run += dpre2[cc]; dpre2[cc] = run; }
        } else if (tid == 2 * DH + 1 && ps_ == 0) {
            float run = 0.f; dsuf1[NCH] = 0.f; dsuf1[NCH + 1] = 0.f;
            for (int cc = NCH - 1; cc >= 0; --cc) { run += dsuf1[cc]; dsuf1[cc] = run; }
        }
        __syncthreads();

        // P6: per-query combine (<=16-key partials on each side of split)
        {
            const int d  = tid & 7;
            const int qs = tid >> 3;      // 0..31
            for (int ql = qs; ql < 256; ql += 32) {
                const int q  = qz * 256 + ql;
                const int p  = (int)pS[ql];
                const int cp = p >> 4;
                float acc2 = pre2[cp][d], den2 = dpre2[cp];
                for (int j = cp << 4; j < p; ++j) {
                    float w = e2S[j];
                    acc2 = fmaf(w, hS[j][d], acc2);
                    den2 += w;
                }
                float acc1 = suf1[cp + 1][d], den1 = dsuf1[cp + 1];
                const int je = min((cp << 4) + CH, N_);
                for (int j = p; j < je; ++j) {
                    float w = e1S[j];
                    acc1 = fmaf(w, hS[j][d], acc1);
                    den1 += w;
                }
                const float A  = AS[ql];
                const float Bv = BS[ql];
                const float den = A * den1 + Bv * den2;
                const float inv = (den > 0.f) ? 1.f / den : 0.f;
                out[(size_t)(base + q) * IND + h * D_ + ps_ * DH + d] =
                    (A * acc1 + Bv * acc2) * inv;
            }
        }
        __syncthreads();
    }
}

extern "C" void kernel_launch(void* const* d_in, const int* in_sizes, int n_in,
                              void* d_out, int out_size, void* d_ws, size_t ws_size,
                              hipStream_t stream) {
    const float* x     = (const float*)d_in[0];
    const float* alive = (const float*)d_in[1];
    const float* W     = (const float*)d_in[2];
    const float* a_src = (const float*)d_in[3];
    const float* a_dst = (const float*)d_in[4];
    float* out = (float*)d_out;

    float* h_ws  = (float*)d_ws;                 // 4 MiB
    float* s_ws  = h_ws  + (size_t)B_ * N_ * IND;
    float* t_ws  = s_ws  + (size_t)B_ * N_ * H_;
    float* e1_ws = t_ws  + (size_t)B_ * N_ * H_;
    float* e2_ws = e1_ws + (size_t)B_ * N_ * H_; // ~4.5 MiB total

    k_h_alpha<<<B_ * N_ / 4, 512, 0, stream>>>(x, alive, W, a_src, a_dst,
                                               h_ws, s_ws, t_ws, e1_ws, e2_ws);

    dim3 g2(H_, B_, 4);
    k_attn2<<<g2, 256, 0, stream>>>(h_ws, s_ws, t_ws, e1_ws, e2_ws, out);
}

// Round 5
// 78.635 us; speedup vs baseline: 2.4690x; 1.4419x over previous
//
#include <hip/hip_runtime.h>
#include <hip/hip_bf16.h>

// GAT layer, B=8 N=1024 IN=128 H=4 D=32. Inputs f32, OUTPUT f32.
//
// k1      : h = x@W^T (W bf16 in LDS); s/t/e1/e2 per (row,head), transposed [h][bn].
// k_rank  : rank sort by t per (b,h) via brute-force ranking (fully parallel),
//           scatter t/idx/e1/e2 into sorted order in ws.
// k_scan  : per (b,h): chunk sums of e1*h (suffix) / e2*h (prefix) + denominators,
//           hierarchical scan over 64 chunks, tables -> ws.
// k_comb  : per query: binary search split p (t_k >= -s_q is a sorted suffix),
//           out = (A*suf1[p] + B*pre2[p]) / (A*d1[p] + B*d2[p]) with <=16-key
//           boundary partials per side.

#define B_   8
#define N_   1024
#define BN   (B_ * N_)
#define IND  128
#define H_   4
#define D_   32
#define NEG  0.2f
#define CH   16
#define NCH  (N_ / CH)       // 64
#define QB   64              // queries per k_comb block

typedef float float4_ __attribute__((ext_vector_type(4)));

__device__ __forceinline__ float bf2f(ushort u) {
    union { unsigned int i; float f; } v; v.i = ((unsigned int)u) << 16; return v.f;
}
__device__ __forceinline__ ushort f2bf(float f) {
    union { float f; unsigned int i; } v; v.f = f;
    unsigned int lsb = (v.i >> 16) & 1u;
    v.i += 0x7fffu + lsb;
    return (ushort)(v.i >> 16);
}

// ---------------- Kernel 1: h = x@W^T, alphas, exp factors ----------------
// grid = B*N/4 blocks, 512 threads. Thread t: col c=t&127, row r=t>>7 (of 4).
__global__ __launch_bounds__(512) void k_h_alpha(
    const float* __restrict__ x,      // [B*N,128]
    const float* __restrict__ alive,  // [B*N]
    const float* __restrict__ W,      // [128,128]
    const float* __restrict__ a_src,  // [128]
    const float* __restrict__ a_dst,  // [128]
    float* __restrict__ h_ws,         // [B*N,128]
    float* __restrict__ sT,           // [H][BN]
    float* __restrict__ tT,           // [H][BN]
    float* __restrict__ e1T,          // [H][BN]
    float* __restrict__ e2T)          // [H][BN]
{
    __shared__ float  xs[4][IND];
    __shared__ ushort Wl[IND][134];   // bf16 W; 134 ushorts = 67 words (odd)
    __shared__ float  asrc[IND], adst[IND];

    const int t     = threadIdx.x;
    const int rbase = blockIdx.x * 4;
    const int c     = t & 127;
    const int r     = t >> 7;

    xs[r][c] = x[(size_t)(rbase + r) * IND + c];
    if (t < IND) { asrc[t] = a_src[t]; adst[t] = a_dst[t]; }

    const float2* Wf2 = reinterpret_cast<const float2*>(W);
    #pragma unroll
    for (int i = t; i < 8192; i += 512) {
        float2 w2 = Wf2[i];
        unsigned int u = ((unsigned int)f2bf(w2.y) << 16) | (unsigned int)f2bf(w2.x);
        reinterpret_cast<unsigned int*>(Wl[i >> 6])[i & 63] = u;
    }
    __syncthreads();

    const unsigned int* wrow = reinterpret_cast<const unsigned int*>(Wl[c]);
    float acc = 0.f;
    #pragma unroll
    for (int j = 0; j < 64; ++j) {
        unsigned int u = wrow[j];
        acc = fmaf(xs[r][2 * j],     bf2f((ushort)(u & 0xffffu)), acc);
        acc = fmaf(xs[r][2 * j + 1], bf2f((ushort)(u >> 16)),     acc);
    }
    const int row = rbase + r;
    h_ws[(size_t)row * IND + c] = acc;

    float ps = acc * asrc[c];
    float pt = acc * adst[c];
    #pragma unroll
    for (int m = 16; m >= 1; m >>= 1) {
        ps += __shfl_xor(ps, m);
        pt += __shfl_xor(pt, m);
    }
    if ((t & 31) == 0) {
        int idx = (c >> 5) * BN + row;      // transposed [h][bn]
        sT[idx] = ps;
        tT[idx] = pt;
        float am = (alive[row] >= 0.5f) ? 1.f : 0.f;
        e1T[idx] = am * __expf(pt);
        e2T[idx] = am * __expf(NEG * pt);
    }
}

// ---------------- Kernel 2: brute-force rank + scatter --------------------
// grid = (4, H, B), 256 threads. Thread owns key i0 = chunk*256+tid.
__global__ __launch_bounds__(256) void k_rank(
    const float* __restrict__ tT,
    const float* __restrict__ e1T,
    const float* __restrict__ e2T,
    float* __restrict__ tSg,   // [32][N]
    int*   __restrict__ kIg,
    float* __restrict__ e1g,
    float* __restrict__ e2g)
{
    __shared__ float ts[N_];
    const int h = blockIdx.y, b = blockIdx.z;
    const int base = h * BN + b * N_;
    for (int i = threadIdx.x; i < N_; i += 256) ts[i] = tT[base + i];
    __syncthreads();

    const int i0 = blockIdx.x * 256 + threadIdx.x;
    const float mt = ts[i0];
    int rank = 0;
    #pragma unroll 8
    for (int j = 0; j < N_; ++j) {
        float v = ts[j];
        rank += (v < mt) | ((v == mt) & (j < i0));
    }
    const int o = (b * H_ + h) * N_ + rank;
    tSg[o] = mt;
    kIg[o] = i0;
    e1g[o] = e1T[base + i0];
    e2g[o] = e2T[base + i0];
}

// ---------------- Kernel 3: chunk sums + scans per (b,h) ------------------
// grid = (H, B), 256 threads.
__global__ __launch_bounds__(256) void k_scan(
    const float* __restrict__ h_ws,
    const int*   __restrict__ kIg,
    const float* __restrict__ e1g,
    const float* __restrict__ e2g,
    float* __restrict__ pre2g,   // [32][65][32]
    float* __restrict__ suf1g,   // [32][66][32]
    float* __restrict__ dpre2g,  // [32][65]
    float* __restrict__ dsuf1g)  // [32][66]
{
    __shared__ int   kI[N_];
    __shared__ float e1S[N_], e2S[N_];
    __shared__ float pre2[NCH + 1][D_];
    __shared__ float suf1[NCH + 2][D_];
    __shared__ float dpre2[NCH + 1], dsuf1[NCH + 2];

    const int h = blockIdx.x, b = blockIdx.y;
    const int bhi = b * H_ + h;
    const int so  = bhi * N_;
    const int tid = threadIdx.x;

    for (int i = tid; i < N_; i += 256) {
        kI[i]  = kIg[so + i];
        e1S[i] = e1g[so + i];
        e2S[i] = e2g[so + i];
    }
    __syncthreads();

    // chunk sums; cell4 = (cc, dim-group): lanes dg=0..7 of same cc read one
    // 128B row segment per key -> coalesced gathers.
    for (int c4 = tid; c4 < NCH * 8; c4 += 256) {
        int cc = c4 >> 3, dg = c4 & 7;
        float4_ a1 = {0.f, 0.f, 0.f, 0.f}, a2 = {0.f, 0.f, 0.f, 0.f};
        #pragma unroll
        for (int jj = 0; jj < CH; ++jj) {
            int j = cc * CH + jj;
            const float4_ hv = *reinterpret_cast<const float4_*>(
                &h_ws[(size_t)(b * N_ + kI[j]) * IND + h * D_ + dg * 4]);
            a1 += e1S[j] * hv;
            a2 += e2S[j] * hv;
        }
        #pragma unroll
        for (int u = 0; u < 4; ++u) {
            pre2[cc + 1][dg * 4 + u] = a2[u];
            suf1[cc][dg * 4 + u]     = a1[u];
        }
    }
    if (tid < NCH) {
        float s = 0.f;
        #pragma unroll
        for (int jj = 0; jj < CH; ++jj) s += e2S[tid * CH + jj];
        dpre2[tid + 1] = s;
    } else if (tid < 2 * NCH) {
        int cc = tid - NCH;
        float s = 0.f;
        #pragma unroll
        for (int jj = 0; jj < CH; ++jj) s += e1S[cc * CH + jj];
        dsuf1[cc] = s;
    }
    __syncthreads();

    if (tid < D_) {
        float run = 0.f; pre2[0][tid] = 0.f;
        for (int cc = 1; cc <= NCH; ++cc) { run += pre2[cc][tid]; pre2[cc][tid] = run; }
    } else if (tid < 2 * D_) {
        int d = tid - D_; float run = 0.f;
        suf1[NCH][d] = 0.f; suf1[NCH + 1][d] = 0.f;
        for (int cc = NCH - 1; cc >= 0; --cc) { run += suf1[cc][d]; suf1[cc][d] = run; }
    } else if (tid == 2 * D_) {
        float run = 0.f; dpre2[0] = 0.f;
        for (int cc = 1; cc <= NCH; ++cc) { run += dpre2[cc]; dpre2[cc] = run; }
    } else if (tid == 2 * D_ + 1) {
        float run = 0.f; dsuf1[NCH] = 0.f; dsuf1[NCH + 1] = 0.f;
        for (int cc = NCH - 1; cc >= 0; --cc) { run += dsuf1[cc]; dsuf1[cc] = run; }
    }
    __syncthreads();

    const float* p2 = &pre2[0][0];
    const float* s1 = &suf1[0][0];
    for (int i = tid; i < (NCH + 1) * D_; i += 256) pre2g[bhi * (NCH + 1) * D_ + i] = p2[i];
    for (int i = tid; i < (NCH + 2) * D_; i += 256) suf1g[bhi * (NCH + 2) * D_ + i] = s1[i];
    if (tid < NCH + 1) dpre2g[bhi * (NCH + 1) + tid] = dpre2[tid];
    else if (tid < (NCH + 1) + (NCH + 2)) {
        int i = tid - (NCH + 1);
        dsuf1g[bhi * (NCH + 2) + i] = dsuf1[i];
    }
}

// ---------------- Kernel 4: per-query combine -----------------------------
// grid = (N/QB, H, B), 512 threads: 64 queries x 8 dim-groups.
__global__ __launch_bounds__(512) void k_comb(
    const float* __restrict__ h_ws,
    const float* __restrict__ sT,
    const float* __restrict__ tSg,
    const int*   __restrict__ kIg,
    const float* __restrict__ e1g,
    const float* __restrict__ e2g,
    const float* __restrict__ pre2g,
    const float* __restrict__ suf1g,
    const float* __restrict__ dpre2g,
    const float* __restrict__ dsuf1g,
    float* __restrict__ out)
{
    __shared__ float tS[N_];
    __shared__ int   kI[N_];
    __shared__ float e1S[N_], e2S[N_];
    __shared__ float pre2[NCH + 1][D_];
    __shared__ float suf1[NCH + 2][D_];
    __shared__ float dpre2[NCH + 1], dsuf1[NCH + 2];

    const int h = blockIdx.y, b = blockIdx.z, qb = blockIdx.x;
    const int bhi = b * H_ + h;
    const int so  = bhi * N_;
    const int tid = threadIdx.x;

    for (int i = tid; i < N_; i += 512) {
        tS[i]  = tSg[so + i];
        kI[i]  = kIg[so + i];
        e1S[i] = e1g[so + i];
        e2S[i] = e2g[so + i];
    }
    for (int i = tid; i < (NCH + 1) * D_; i += 512) (&pre2[0][0])[i] = pre2g[bhi * (NCH + 1) * D_ + i];
    for (int i = tid; i < (NCH + 2) * D_; i += 512) (&suf1[0][0])[i] = suf1g[bhi * (NCH + 2) * D_ + i];
    if (tid < NCH + 1) dpre2[tid] = dpre2g[bhi * (NCH + 1) + tid];
    else if (tid < (NCH + 1) + (NCH + 2)) {
        int i = tid - (NCH + 1);
        dsuf1[i] = dsuf1g[bhi * (NCH + 2) + i];
    }
    __syncthreads();

    const int ql  = tid >> 3;         // 0..63
    const int sub = tid & 7;          // dim group
    const int q   = qb * QB + ql;

    const float s  = sT[h * BN + b * N_ + q];
    const float A  = __expf(s);
    const float Bv = __expf(NEG * s);
    const float tau = -s;
    int lo = 0, hi = N_;
    #pragma unroll
    for (int it = 0; it < 10; ++it) {
        int mid = (lo + hi) >> 1;
        if (tS[mid] >= tau) hi = mid; else lo = mid + 1;
    }
    const int p  = lo;
    const int cp = p >> 4;

    float4_ acc2 = *reinterpret_cast<const float4_*>(&pre2[cp][sub * 4]);
    float   den2 = dpre2[cp];
    for (int j = cp << 4; j < p; ++j) {
        float w = e2S[j];
        const float4_ hv = *reinterpret_cast<const float4_*>(
            &h_ws[(size_t)(b * N_ + kI[j]) * IND + h * D_ + sub * 4]);
        acc2 += w * hv;
        den2 += w;
    }
    float4_ acc1 = *reinterpret_cast<const float4_*>(&suf1[cp + 1][sub * 4]);
    float   den1 = dsuf1[cp + 1];
    const int je = min((cp << 4) + CH, N_);
    for (int j = p; j < je; ++j) {
        float w = e1S[j];
        const float4_ hv = *reinterpret_cast<const float4_*>(
            &h_ws[(size_t)(b * N_ + kI[j]) * IND + h * D_ + sub * 4]);
        acc1 += w * hv;
        den1 += w;
    }

    const float den = A * den1 + Bv * den2;
    const float inv = (den > 0.f) ? 1.f / den : 0.f;
    float4_ r = (A * acc1 + Bv * acc2) * inv;
    *reinterpret_cast<float4_*>(&out[(size_t)(b * N_ + q) * IND + h * D_ + sub * 4]) = r;
}

extern "C" void kernel_launch(void* const* d_in, const int* in_sizes, int n_in,
                              void* d_out, int out_size, void* d_ws, size_t ws_size,
                              hipStream_t stream) {
    const float* x     = (const float*)d_in[0];
    const float* alive = (const float*)d_in[1];
    const float* W     = (const float*)d_in[2];
    const float* a_src = (const float*)d_in[3];
    const float* a_dst = (const float*)d_in[4];
    float* out = (float*)d_out;

    float* h_ws   = (float*)d_ws;               // BN*128
    float* sT     = h_ws + (size_t)BN * IND;    // [H][BN]
    float* tT     = sT  + (size_t)H_ * BN;
    float* e1T    = tT  + (size_t)H_ * BN;
    float* e2T    = e1T + (size_t)H_ * BN;
    float* tSg    = e2T + (size_t)H_ * BN;      // [32][N]
    int*   kIg    = (int*)(tSg + 32 * N_);
    float* e1g    = (float*)(kIg + 32 * N_);
    float* e2g    = e1g + 32 * N_;
    float* pre2g  = e2g + 32 * N_;              // 32*65*32
    float* suf1g  = pre2g + 32 * (NCH + 1) * D_;
    float* dpre2g = suf1g + 32 * (NCH + 2) * D_;
    float* dsuf1g = dpre2g + 32 * (NCH + 1);    // total ~5.6 MB

    k_h_alpha<<<BN / 4, 512, 0, stream>>>(x, alive, W, a_src, a_dst,
                                          h_ws, sT, tT, e1T, e2T);

    dim3 g2(N_ / 256, H_, B_);
    k_rank<<<g2, 256, 0, stream>>>(tT, e1T, e2T, tSg, kIg, e1g, e2g);

    dim3 g3(H_, B_);
    k_scan<<<g3, 256, 0, stream>>>(h_ws, kIg, e1g, e2g,
                                   pre2g, suf1g, dpre2g, dsuf1g);

    dim3 g4(N_ / QB, H_, B_);
    k_comb<<<g4, 512, 0, stream>>>(h_ws, sT, tSg, kIg, e1g, e2g,
                                   pre2g, suf1g, dpre2g, dsuf1g, out);
}